// Round 3
// baseline (3467.232 us; speedup 1.0000x reference)
//
#include <hip/hip_runtime.h>
#include <cmath>

#define TSTEPS 256
#define DIM 1024
#define GST 35            // gate scratch col-stride

typedef _Float16 half8v __attribute__((ext_vector_type(8)));
typedef _Float16 half4v __attribute__((ext_vector_type(4)));
typedef float f32x4 __attribute__((ext_vector_type(4)));
typedef unsigned long long u64;

// ws layout:
//   xh  : [T][B][D] fp16 x (t-major), 16,777,216 halfs
//   h0r : [4 slot][64][1024] ring for h0
//   h1r : [4 slot][64][1024] ring for h1
//   cnts: leaf0[p][16 leaves, 16-word stride], leaf1[...] (131,072 uints)
// Phase p: cell0 computes h0[t=p] (reads x[p], h0[p-1]); cell1 computes
// h1[t=p-1] (reads h0[p-1], h1[p-2]). h[t] in ring slot t&3.
//
// R9: h broadcast through per-XCD L2 (producer: coalesced 8B agent stores;
//     consumer: agent-acquire invalidate, then plain cached half8v loads).
// R10: acquire-fence instead of acquire-load; tid0 signals right after
//      wave0's vmcnt(0); (s_sleep pacing tweak).
// R11 (this round): DVFS experiment. Measured effective clock ~750MHz
// (MfmaUtil 6.7% vs exact 620 busy cy/SIMD/phase -> 9.25k cy/phase @13us).
// 95% of waves were ASLEEP (7/8 at s_barrier, wave0 in s_sleep) -> governor
// parks SCLK. Keep the CU hot during waits:
//   - waves 1-7 spin on an LDS per-phase flag (written by wave0 post-poll)
//     with dependent v_fma burn, then hit the now-instant __syncthreads.
//     Flag is a pre-wake only; ALL ordering still comes from the barrier.
//   - wave0 poll pacing: s_sleep(4) -> ~256cy fma burn (same poll traffic).

__device__ __forceinline__ void burn(int n) {
    float x = 1.0f;
    #pragma unroll 4
    for (int i = 0; i < n; ++i)
        asm volatile("v_fma_f32 %0, %0, %0, %0" : "+v"(x));
}

__global__ void prologue(const float* __restrict__ x, _Float16* __restrict__ xh,
                         _Float16* __restrict__ hrings, unsigned* __restrict__ cnts)
{
    size_t gid  = (size_t)blockIdx.x * blockDim.x + threadIdx.x;
    size_t nthr = (size_t)gridDim.x * blockDim.x;
    for (size_t i = gid; i < 4194304u; i += nthr) {     // x[b][t][d4] -> xh[t][b][d]
        float4 v = ((const float4*)x)[i];
        half4v h = {(_Float16)v.x, (_Float16)v.y, (_Float16)v.z, (_Float16)v.w};
        unsigned d4 = (unsigned)i & 255u, t = ((unsigned)i >> 8) & 255u, b = (unsigned)i >> 16;
        ((half4v*)(xh + ((size_t)t * 64 + b) * 1024))[d4] = h;
    }
    for (size_t i = gid; i < 65536u; i += nthr) {       // zero both h rings
        half8v z = {};
        ((half8v*)hrings)[i] = z;
    }
    for (size_t i = gid; i < 139264u; i += nthr) cnts[i] = 0u;
}

// 256 blocks x 512 threads (8 waves). Blocks 0..127: cell0; 128..255: cell1.
// Block owns 32 gate-cols = 8 h-dims. Wave kq owns K-slice [kq*256,+256),
// weights in registers (16 x half8v). A held as A[4][8], loaded in one
// 32-load burst. Signal: 16 leaf counters/cell/phase (8 adds each, 64B
// apart). Wait: wave 0 lanes 0..31 poll all leaves of BOTH dep sets in
// parallel + ballot, latch satisfied lanes.
__global__ __launch_bounds__(512, 2)
void lstm_persistent(const float* __restrict__ Wx0, const float* __restrict__ Wh0,
                     const float* __restrict__ b0,
                     const float* __restrict__ Wx1, const float* __restrict__ Wh1,
                     const float* __restrict__ b1,
                     const _Float16* __restrict__ xh, _Float16* __restrict__ h0r,
                     _Float16* __restrict__ h1r, unsigned* __restrict__ cnts,
                     float* __restrict__ out)
{
    extern __shared__ char smem[];
    _Float16* wfrag = (_Float16*)smem;          // 128 KB staging (dead after init)
    float*    gates = (float*)smem;             // [8 kq][64 m][GST] fp32, aliases
    _Float16* hlds  = (_Float16*)(smem + 102400); // [64][8] h gather (above gates' 71.7KB)
    unsigned* pflag = (unsigned*)(smem + 110592); // per-phase wake flag (R11)

    const int tid  = threadIdx.x;
    const int blk  = blockIdx.x;
    const int cell = blk >> 7;
    const int wb   = blk & 127;
    const int lane = tid & 63, kq = tid >> 6;
    const int n15 = lane & 15, q = lane >> 4;

    unsigned* leaf0 = cnts;                     // [(p*16+leaf)*16]
    unsigned* leaf1 = cnts + 65536;
    unsigned* leafm = cell ? leaf1 : leaf0;

    // ---- one-time: weights -> LDS in B-fragment order (fp32->fp16) ----
    const float* m0 = cell ? Wx1 : Wx0;
    const float* m1 = cell ? Wh1 : Wh0;
    for (int idx = tid; idx < 16384; idx += 512) {
        int k = idx >> 3;
        int cc0 = (idx & 7) * 4;
        int g = cc0 >> 3, c = cc0 & 7;
        const float* src = (k < 1024 ? m0 + (size_t)k * 4096
                                     : m1 + (size_t)(k - 1024) * 4096)
                           + g * 1024 + wb * 8 + c;
        float4 v = *(const float4*)src;
        int skq = k >> 8, kt = (k >> 5) & 7, sq = (k >> 3) & 3, j = k & 7;
        float vv[4] = {v.x, v.y, v.z, v.w};
        #pragma unroll
        for (int e = 0; e < 4; ++e) {
            int cc = cc0 + e, nt = cc >> 4, nn = cc & 15;
            wfrag[((((skq * 2 + nt) * 8 + kt) * 64) + sq * 16 + nn) * 8 + j] = (_Float16)vv[e];
        }
    }
    __syncthreads();

    half8v wreg[16];                      // [nt*8 + kt]
    #pragma unroll
    for (int nt = 0; nt < 2; ++nt)
        #pragma unroll
        for (int kt = 0; kt < 8; ++kt)
            wreg[nt * 8 + kt] = *(const half8v*)
                &wfrag[((((kq * 2 + nt) * 8 + kt) * 64) + lane) * 8];
    __syncthreads();                      // wfrag dead; gates alias it

    const int pb = tid >> 3, pd = tid & 7;
    const float* bias = cell ? b1 : b0;
    const int gdim = wb * 8 + pd;
    const float bi = bias[0 * 1024 + gdim], bfg = bias[1 * 1024 + gdim],
                bg = bias[2 * 1024 + gdim], bo  = bias[3 * 1024 + gdim];
    float creg = 0.0f;

    const bool havex = (cell == 0) && (kq < 4);   // x-wave: plain cached loads

    for (int p = 0; p <= TSTEPS; ++p) {
        if (cell == 0 && p == TSTEPS) break;
        const bool active = cell ? (p >= 1) : true;

        half8v A[4][8];
        // x burst BEFORE the poll (no coherence needed; overlaps the wait)
        if (havex) {
            const _Float16* a = xh + (size_t)p * 65536 + (size_t)n15 * 1024
                                + kq * 256 + q * 8;
            #pragma unroll
            for (int mt = 0; mt < 4; ++mt)
                #pragma unroll
                for (int kt = 0; kt < 8; ++kt)
                    A[mt][kt] = *(const half8v*)(a + mt * 16384 + kt * 32);
        }

        // ---- wait for dependencies ----
        // wave 0: leaf-parallel global poll + ballot, fma-burn pacing.
        // waves 1-7: hot-spin on LDS flag (pre-wake; ordering still via B1).
        if (tid < 64) {
            if (p >= 1) {
                // set A: leaf0[p-1] (lanes 0..15). set B (lanes 16..31):
                //   cell0: leaf1[p-3] (ring WAR), cell1: leaf1[p-1]
                const unsigned* addr = nullptr;
                if (tid < 16) {
                    addr = leaf0 + ((p - 1) * 16 + tid) * 16;
                } else if (tid < 32) {
                    int lf = tid - 16;
                    if (cell == 0) { if (p >= 3) addr = leaf1 + ((p - 3) * 16 + lf) * 16; }
                    else           { if (p >= 2) addr = leaf1 + ((p - 1) * 16 + lf) * 16; }
                }
                bool ok = (addr == nullptr);
                while (true) {
                    if (!ok)
                        ok = __hip_atomic_load(addr, __ATOMIC_RELAXED,
                                               __HIP_MEMORY_SCOPE_AGENT) >= 8u;
                    if (__ballot(ok) == ~0ull) break;
                    burn(64);                         // ~256cy, SIMD stays hot
                }
            }
            // ACQUIRE fence: buffer_inv (no dependent load) -> drop possibly
            // stale L1/L2 h lines; plain cached loads below refetch from L3.
            __builtin_amdgcn_fence(__ATOMIC_ACQUIRE, "agent");
            if (tid == 0)
                __hip_atomic_store(pflag, (unsigned)p, __ATOMIC_RELAXED,
                                   __HIP_MEMORY_SCOPE_WORKGROUP);
        } else if (p >= 1) {
            while (__hip_atomic_load(pflag, __ATOMIC_RELAXED,
                                     __HIP_MEMORY_SCOPE_WORKGROUP) < (unsigned)p)
                burn(16);                             // ~64cy LDS re-check
        }
        __syncthreads();

        // ---- h burst: plain cached loads (L2 dedups across the XCD) ----
        if (active && !havex) {
            const _Float16* arow;
            if (cell == 0) {
                arow = h0r + (size_t)((p - 1) & 3) * 65536 + (kq - 4) * 256;
            } else {
                arow = (kq < 4) ? h0r + (size_t)((p - 1) & 3) * 65536 + kq * 256
                                : h1r + (size_t)((p - 2) & 3) * 65536 + (kq - 4) * 256;
            }
            const _Float16* a = arow + (size_t)n15 * 1024 + q * 8;
            #pragma unroll
            for (int mt = 0; mt < 4; ++mt)
                #pragma unroll
                for (int kt = 0; kt < 8; ++kt)
                    A[mt][kt] = *(const half8v*)(a + mt * 16384 + kt * 32);
        }

        // ---- MFMA ----
        if (active) {
            #pragma unroll
            for (int mt = 0; mt < 4; ++mt) {
                f32x4 acc0 = {0.f, 0.f, 0.f, 0.f};
                f32x4 acc1 = {0.f, 0.f, 0.f, 0.f};
                #pragma unroll
                for (int kt = 0; kt < 8; ++kt) {
                    acc0 = __builtin_amdgcn_mfma_f32_16x16x32_f16(A[mt][kt], wreg[kt],     acc0, 0, 0, 0);
                    acc1 = __builtin_amdgcn_mfma_f32_16x16x32_f16(A[mt][kt], wreg[8 + kt], acc1, 0, 0, 0);
                }
                const int row0 = mt * 16 + q * 4;
                #pragma unroll
                for (int r = 0; r < 4; ++r) {
                    gates[(kq * 64 + row0 + r) * GST + n15]      = acc0[r];
                    gates[(kq * 64 + row0 + r) * GST + 16 + n15] = acc1[r];
                }
            }
        }
        __syncthreads();

        // ---- pointwise -> gather h into LDS ----
        if (active) {
            float g0 = 0.f, g1 = 0.f, g2 = 0.f, g3 = 0.f;
            #pragma unroll
            for (int k8 = 0; k8 < 8; ++k8) {
                const float* gsr = gates + (k8 * 64 + pb) * GST + pd;
                g0 += gsr[0]; g1 += gsr[8]; g2 += gsr[16]; g3 += gsr[24];
            }
            g0 += bi; g1 += bfg; g2 += bg; g3 += bo;
            float si = 1.f / (1.f + __expf(-g0));
            float sf = 1.f / (1.f + __expf(-g1));
            float so = 1.f / (1.f + __expf(-g3));
            float cn = sf * creg + si * tanhf(g2);
            float hn = so * tanhf(cn);
            creg = cn;
            hlds[pb * 8 + pd] = (_Float16)hn;
            if (cell && p == TSTEPS) out[pb * 1024 + gdim] = hn;
        }

        // ---- h store + signal: wave 0 only; tid0 adds right after vmcnt(0)
        //      (no trailing barrier on the signal path) ----
        if (p < TSTEPS) {
            if (active) __syncthreads();              // hlds visible to wave 0
            if (tid < 64) {
                if (active) {
                    const u64* hp = (const u64*)(hlds + tid * 8);
                    u64 lo = hp[0], hi = hp[1];
                    _Float16* dst = cell ? (h1r + (size_t)((p - 1) & 3) * 65536)
                                         : (h0r + (size_t)(p & 3) * 65536);
                    u64* dp = (u64*)(dst + (size_t)tid * 1024 + wb * 8);
                    __hip_atomic_store(dp,     lo, __ATOMIC_RELAXED, __HIP_MEMORY_SCOPE_AGENT);
                    __hip_atomic_store(dp + 1, hi, __ATOMIC_RELAXED, __HIP_MEMORY_SCOPE_AGENT);
                    asm volatile("s_waitcnt vmcnt(0)" ::: "memory");   // h at L3
                }
                if (tid == 0)
                    __hip_atomic_fetch_add(leafm + (p * 16 + (wb >> 3)) * 16, 1u,
                                           __ATOMIC_RELAXED, __HIP_MEMORY_SCOPE_AGENT);
            }
        }
    }
}

extern "C" void kernel_launch(void* const* d_in, const int* in_sizes, int n_in,
                              void* d_out, int out_size, void* d_ws, size_t ws_size,
                              hipStream_t stream)
{
    const float* x   = (const float*)d_in[0];
    const float* Wx0 = (const float*)d_in[1];
    const float* Wh0 = (const float*)d_in[2];
    const float* b0  = (const float*)d_in[3];
    const float* Wx1 = (const float*)d_in[4];
    const float* Wh1 = (const float*)d_in[5];
    const float* b1  = (const float*)d_in[6];
    float* out = (float*)d_out;

    _Float16* xh   = (_Float16*)d_ws;
    _Float16* h0r  = xh + (size_t)16777216;
    _Float16* h1r  = h0r + 262144;
    unsigned* cnts = (unsigned*)(h1r + 262144);

    hipLaunchKernelGGL(prologue, dim3(2048), dim3(256), 0, stream, x, xh, h0r, cnts);

    size_t smem = 131072;
    (void)hipFuncSetAttribute((const void*)lstm_persistent,
                              hipFuncAttributeMaxDynamicSharedMemorySize, (int)smem);

    void* args[] = {(void*)&Wx0, (void*)&Wh0, (void*)&b0,
                    (void*)&Wx1, (void*)&Wh1, (void*)&b1,
                    (void*)&xh, (void*)&h0r, (void*)&h1r,
                    (void*)&cnts, (void*)&out};
    (void)hipLaunchCooperativeKernel((const void*)lstm_persistent, dim3(256), dim3(512),
                                     args, (unsigned)smem, stream);
}

// Round 4
// 2311.848 us; speedup vs baseline: 1.4998x; 1.4998x over previous
//
#include <hip/hip_runtime.h>
#include <cmath>

#define TSTEPS 256
#define DIM 1024

typedef _Float16 half8v __attribute__((ext_vector_type(8)));
typedef _Float16 half4v __attribute__((ext_vector_type(4)));
typedef float f32x4 __attribute__((ext_vector_type(4)));
typedef unsigned long long u64;

// ws layout:
//   xh  : [T][B][D] fp16 x (t-major), 16,777,216 halfs
//   h0r : [4 slot][128 wb][64 b][8 d] BLOCKED ring for h0 (R12)
//   h1r : same, for h1
//   cnts: leaf0[p][16 leaves, 16-word stride], leaf1[...] (131,072 uints)
// Phase p: cell0 computes h0[t=p] (reads x[p], h0[p-1]); cell1 computes
// h1[t=p-1] (reads h0[p-1], h1[p-2]). h[t] in ring slot t&3.
//
// R9:  h broadcast through per-XCD L2 (agent stores; acquire-inv; cached loads).
// R10: acquire-fence; tid0 signals right after wave0's vmcnt(0).
// R11: burn-spin experiment -> NULL. Bounded waits at ~20% of wall; ~65% is
//      compute-path memory stalls. Reverted the spin.
// R12 (this round): attack the two named stall sources:
//   1) gates LDS: layout [c:32][kq:8][m:64] + XOR swizzle (idx ^= (c&7)<<2).
//      Writes: 8x ds_write_b128/thread (was 32x b32), conflict-free quads.
//      Reads: 32x b32 at exactly 2-way (free). Was 1570 conflict-cy/CU-phase.
//   2) h rings BLOCKED [wb][b][8d]: producer stores contiguous 1KB/block
//      (WRITE_SIZE 264->~80MB, faster vmcnt(0) drain); consumer reads 256B runs.
//   3) tanhf -> __expf-based (2 ocml chains off the serial pointwise path).

__global__ void prologue(const float* __restrict__ x, _Float16* __restrict__ xh,
                         _Float16* __restrict__ hrings, unsigned* __restrict__ cnts)
{
    size_t gid  = (size_t)blockIdx.x * blockDim.x + threadIdx.x;
    size_t nthr = (size_t)gridDim.x * blockDim.x;
    for (size_t i = gid; i < 4194304u; i += nthr) {     // x[b][t][d4] -> xh[t][b][d]
        float4 v = ((const float4*)x)[i];
        half4v h = {(_Float16)v.x, (_Float16)v.y, (_Float16)v.z, (_Float16)v.w};
        unsigned d4 = (unsigned)i & 255u, t = ((unsigned)i >> 8) & 255u, b = (unsigned)i >> 16;
        ((half4v*)(xh + ((size_t)t * 64 + b) * 1024))[d4] = h;
    }
    for (size_t i = gid; i < 65536u; i += nthr) {       // zero both h rings
        half8v z = {};
        ((half8v*)hrings)[i] = z;
    }
    for (size_t i = gid; i < 139264u; i += nthr) cnts[i] = 0u;
}

// 256 blocks x 512 threads (8 waves). Blocks 0..127: cell0; 128..255: cell1.
// Block owns 32 gate-cols = 8 h-dims. Wave kq owns K-slice [kq*256,+256),
// weights in registers (16 x half8v). A held as A[4][8], loaded in one
// 32-load burst. Signal: 16 leaf counters/cell/phase (8 adds each, 64B
// apart). Wait: wave 0 lanes 0..31 poll all leaves of BOTH dep sets in
// parallel + ballot, s_sleep(4) pacing, latch satisfied lanes.
__global__ __launch_bounds__(512, 2)
void lstm_persistent(const float* __restrict__ Wx0, const float* __restrict__ Wh0,
                     const float* __restrict__ b0,
                     const float* __restrict__ Wx1, const float* __restrict__ Wh1,
                     const float* __restrict__ b1,
                     const _Float16* __restrict__ xh, _Float16* __restrict__ h0r,
                     _Float16* __restrict__ h1r, unsigned* __restrict__ cnts,
                     float* __restrict__ out)
{
    extern __shared__ char smem[];
    _Float16* wfrag = (_Float16*)smem;          // 128 KB staging (dead after init)
    float*    gates = (float*)smem;             // [32 c][8 kq][64 m] fp32 ^swz, 64KB
    _Float16* hlds  = (_Float16*)(smem + 102400); // [64 b][8 d] h gather

    const int tid  = threadIdx.x;
    const int blk  = blockIdx.x;
    const int cell = blk >> 7;
    const int wb   = blk & 127;
    const int lane = tid & 63, kq = tid >> 6;
    const int n15 = lane & 15, q = lane >> 4;

    unsigned* leaf0 = cnts;                     // [(p*16+leaf)*16]
    unsigned* leaf1 = cnts + 65536;
    unsigned* leafm = cell ? leaf1 : leaf0;

    // ---- one-time: weights -> LDS in B-fragment order (fp32->fp16) ----
    const float* m0 = cell ? Wx1 : Wx0;
    const float* m1 = cell ? Wh1 : Wh0;
    for (int idx = tid; idx < 16384; idx += 512) {
        int k = idx >> 3;
        int cc0 = (idx & 7) * 4;
        int g = cc0 >> 3, c = cc0 & 7;
        const float* src = (k < 1024 ? m0 + (size_t)k * 4096
                                     : m1 + (size_t)(k - 1024) * 4096)
                           + g * 1024 + wb * 8 + c;
        float4 v = *(const float4*)src;
        int skq = k >> 8, kt = (k >> 5) & 7, sq = (k >> 3) & 3, j = k & 7;
        float vv[4] = {v.x, v.y, v.z, v.w};
        #pragma unroll
        for (int e = 0; e < 4; ++e) {
            int cc = cc0 + e, nt = cc >> 4, nn = cc & 15;
            wfrag[((((skq * 2 + nt) * 8 + kt) * 64) + sq * 16 + nn) * 8 + j] = (_Float16)vv[e];
        }
    }
    __syncthreads();

    half8v wreg[16];                      // [nt*8 + kt]
    #pragma unroll
    for (int nt = 0; nt < 2; ++nt)
        #pragma unroll
        for (int kt = 0; kt < 8; ++kt)
            wreg[nt * 8 + kt] = *(const half8v*)
                &wfrag[((((kq * 2 + nt) * 8 + kt) * 64) + lane) * 8];
    __syncthreads();                      // wfrag dead; gates alias it

    const int pb = tid >> 3, pd = tid & 7;
    const float* bias = cell ? b1 : b0;
    const int gdim = wb * 8 + pd;
    const float bi = bias[0 * 1024 + gdim], bfg = bias[1 * 1024 + gdim],
                bg = bias[2 * 1024 + gdim], bo  = bias[3 * 1024 + gdim];
    float creg = 0.0f;

    const bool havex = (cell == 0) && (kq < 4);   // x-wave: plain cached loads
    const int  xw    = (n15 & 7) << 2;            // gates XOR key (write side)
    const int  xrr   = (pd & 7) << 2;             // gates XOR key (read side)

    for (int p = 0; p <= TSTEPS; ++p) {
        if (cell == 0 && p == TSTEPS) break;
        const bool active = cell ? (p >= 1) : true;

        half8v A[4][8];
        // x burst BEFORE the poll (no coherence needed; overlaps the wait)
        if (havex) {
            const _Float16* a = xh + (size_t)p * 65536 + (size_t)n15 * 1024
                                + kq * 256 + q * 8;
            #pragma unroll
            for (int mt = 0; mt < 4; ++mt)
                #pragma unroll
                for (int kt = 0; kt < 8; ++kt)
                    A[mt][kt] = *(const half8v*)(a + mt * 16384 + kt * 32);
        }

        // ---- wait for dependencies: wave 0, leaf-parallel + ballot ----
        if (tid < 64) {
            if (p >= 1) {
                // set A: leaf0[p-1] (lanes 0..15). set B (lanes 16..31):
                //   cell0: leaf1[p-3] (ring WAR), cell1: leaf1[p-1]
                const unsigned* addr = nullptr;
                if (tid < 16) {
                    addr = leaf0 + ((p - 1) * 16 + tid) * 16;
                } else if (tid < 32) {
                    int lf = tid - 16;
                    if (cell == 0) { if (p >= 3) addr = leaf1 + ((p - 3) * 16 + lf) * 16; }
                    else           { if (p >= 2) addr = leaf1 + ((p - 1) * 16 + lf) * 16; }
                }
                bool ok = (addr == nullptr);
                while (true) {
                    if (!ok)
                        ok = __hip_atomic_load(addr, __ATOMIC_RELAXED,
                                               __HIP_MEMORY_SCOPE_AGENT) >= 8u;
                    if (__ballot(ok) == ~0ull) break;
                    __builtin_amdgcn_s_sleep(4);
                }
            }
            // ACQUIRE fence: buffer_inv -> drop possibly stale L1/L2 h lines;
            // plain cached loads below refetch from L3.
            __builtin_amdgcn_fence(__ATOMIC_ACQUIRE, "agent");
        }
        __syncthreads();

        // ---- h burst: plain cached loads from BLOCKED ring ----
        if (active && !havex) {
            const _Float16* hb;
            int wq;
            if (cell == 0)      { hb = h0r + (size_t)((p - 1) & 3) * 65536; wq = (kq - 4) * 32; }
            else if (kq < 4)    { hb = h0r + (size_t)((p - 1) & 3) * 65536; wq = kq * 32; }
            else                { hb = h1r + (size_t)((p - 2) & 3) * 65536; wq = (kq - 4) * 32; }
            // elem (b, d): hb[(d>>3)*512 + b*8 + (d&7)]; lane dims d = wq*8+kt*32+q*8
            const _Float16* a = hb + (size_t)(wq + q) * 512 + (size_t)n15 * 8;
            #pragma unroll
            for (int mt = 0; mt < 4; ++mt)
                #pragma unroll
                for (int kt = 0; kt < 8; ++kt)
                    A[mt][kt] = *(const half8v*)(a + kt * 2048 + mt * 128);
        }

        // ---- MFMA; gate partials -> swizzled LDS via ds_write_b128 ----
        if (active) {
            #pragma unroll
            for (int mt = 0; mt < 4; ++mt) {
                f32x4 acc0 = {0.f, 0.f, 0.f, 0.f};
                f32x4 acc1 = {0.f, 0.f, 0.f, 0.f};
                #pragma unroll
                for (int kt = 0; kt < 8; ++kt) {
                    acc0 = __builtin_amdgcn_mfma_f32_16x16x32_f16(A[mt][kt], wreg[kt],     acc0, 0, 0, 0);
                    acc1 = __builtin_amdgcn_mfma_f32_16x16x32_f16(A[mt][kt], wreg[8 + kt], acc1, 0, 0, 0);
                }
                const int row0 = mt * 16 + q * 4;
                // gates idx = ((c*8 + kq)*64 + m) ^ ((c&7)<<2); m=row0..row0+3
                *(f32x4*)(gates + ((((n15      * 8 + kq) * 64) + row0) ^ xw)) = acc0;
                *(f32x4*)(gates + (((((16+n15) * 8 + kq) * 64) + row0) ^ xw)) = acc1;
            }
        }
        __syncthreads();

        // ---- pointwise: reduce 8 partials/gate, fast tanh, gather h ----
        if (active) {
            float gg[4];
            #pragma unroll
            for (int g = 0; g < 4; ++g) {
                const int c = g * 8 + pd;
                float s = 0.f;
                #pragma unroll
                for (int k8 = 0; k8 < 8; ++k8)
                    s += gates[(((c * 8 + k8) * 64) + pb) ^ xrr];
                gg[g] = s;
            }
            float g0 = gg[0] + bi, g1 = gg[1] + bfg, g2 = gg[2] + bg, g3 = gg[3] + bo;
            float si = 1.f / (1.f + __expf(-g0));
            float sf = 1.f / (1.f + __expf(-g1));
            float so = 1.f / (1.f + __expf(-g3));
            float tg = 1.f - 2.f / (__expf(2.f * g2) + 1.f);
            float cn = sf * creg + si * tg;
            float tc = 1.f - 2.f / (__expf(2.f * cn) + 1.f);
            float hn = so * tc;
            creg = cn;
            hlds[pb * 8 + pd] = (_Float16)hn;
            if (cell && p == TSTEPS) out[pb * 1024 + gdim] = hn;
        }

        // ---- h store (BLOCKED, contiguous 1KB) + signal ----
        if (p < TSTEPS) {
            if (active) __syncthreads();              // hlds visible to wave 0
            if (tid < 64) {
                if (active) {
                    const u64* hp = (const u64*)(hlds + tid * 8);
                    u64 lo = hp[0], hi = hp[1];
                    _Float16* dst = (cell ? h1r + (size_t)((p - 1) & 3) * 65536
                                          : h0r + (size_t)(p & 3) * 65536)
                                    + (size_t)wb * 512;
                    u64* dp = (u64*)dst + tid * 2;    // lane-contiguous 16B
                    __hip_atomic_store(dp,     lo, __ATOMIC_RELAXED, __HIP_MEMORY_SCOPE_AGENT);
                    __hip_atomic_store(dp + 1, hi, __ATOMIC_RELAXED, __HIP_MEMORY_SCOPE_AGENT);
                    asm volatile("s_waitcnt vmcnt(0)" ::: "memory");   // h at L3
                }
                if (tid == 0)
                    __hip_atomic_fetch_add(leafm + (p * 16 + (wb >> 3)) * 16, 1u,
                                           __ATOMIC_RELAXED, __HIP_MEMORY_SCOPE_AGENT);
            }
        }
    }
}

extern "C" void kernel_launch(void* const* d_in, const int* in_sizes, int n_in,
                              void* d_out, int out_size, void* d_ws, size_t ws_size,
                              hipStream_t stream)
{
    const float* x   = (const float*)d_in[0];
    const float* Wx0 = (const float*)d_in[1];
    const float* Wh0 = (const float*)d_in[2];
    const float* b0  = (const float*)d_in[3];
    const float* Wx1 = (const float*)d_in[4];
    const float* Wh1 = (const float*)d_in[5];
    const float* b1  = (const float*)d_in[6];
    float* out = (float*)d_out;

    _Float16* xh   = (_Float16*)d_ws;
    _Float16* h0r  = xh + (size_t)16777216;
    _Float16* h1r  = h0r + 262144;
    unsigned* cnts = (unsigned*)(h1r + 262144);

    hipLaunchKernelGGL(prologue, dim3(2048), dim3(256), 0, stream, x, xh, h0r, cnts);

    size_t smem = 131072;
    (void)hipFuncSetAttribute((const void*)lstm_persistent,
                              hipFuncAttributeMaxDynamicSharedMemorySize, (int)smem);

    void* args[] = {(void*)&Wx0, (void*)&Wh0, (void*)&b0,
                    (void*)&Wx1, (void*)&Wh1, (void*)&b1,
                    (void*)&xh, (void*)&h0r, (void*)&h1r,
                    (void*)&cnts, (void*)&out};
    (void)hipLaunchCooperativeKernel((const void*)lstm_persistent, dim3(256), dim3(512),
                                     args, (unsigned)smem, stream);
}

// Round 5
// 2056.732 us; speedup vs baseline: 1.6858x; 1.1240x over previous
//
#include <hip/hip_runtime.h>
#include <cmath>

#define TSTEPS 256
#define DIM 1024

typedef _Float16 half8v __attribute__((ext_vector_type(8)));
typedef _Float16 half4v __attribute__((ext_vector_type(4)));
typedef float f32x4 __attribute__((ext_vector_type(4)));
typedef unsigned long long u64;

// ws layout:
//   xh  : [T][B][D] fp16 x (t-major), 16,777,216 halfs
//   h0r : [4 slot][mb:2][nb:64][b:32][d:16] blocked ring for h0 (R13)
//   h1r : same, for h1
//   cnts: leaf0[p][16 leaves, 16-word stride], leaf1[...] (131,072 uints)
// Phase p: cell0 computes h0[t=p] (reads x[p], h0[p-1]); cell1 computes
// h1[t=p-1] (reads h0[p-1], h1[p-2]). h[t] in ring slot t&3.
//
// R9:  h broadcast via L2 (agent stores; acquire-inv; cached loads).
// R10: acquire-fence; tid0 signals right after wave0's vmcnt(0).
// R11: burn-spin -> NULL (waits ~20% of wall).
// R12: gates XOR-swizzle + blocked h-ring + fast tanh (-33%; conflicts 49x down).
// R13 (this round): per-CU ingest is the wall (~4100cy of the 6140cy phase:
// 256KB A-operands/block through ~60B/cy TA port). Re-tile M x N per block
// 64x32 -> 32x64: A-traffic per block halves to 128KB (work conserved, same
// 64 MFMA/wave). Weights double to 64 cols (128 VGPR/wave, staged in TWO
// 128KB LDS passes). Gates LDS [c:64][kq:8][m:32], same swizzle algebra.
// Block (cell, mb=wb>>6, nb=wb&63) owns batch rows mb*32..+32, h-dims
// nb*16..+16.

__global__ void prologue(const float* __restrict__ x, _Float16* __restrict__ xh,
                         _Float16* __restrict__ hrings, unsigned* __restrict__ cnts)
{
    size_t gid  = (size_t)blockIdx.x * blockDim.x + threadIdx.x;
    size_t nthr = (size_t)gridDim.x * blockDim.x;
    for (size_t i = gid; i < 4194304u; i += nthr) {     // x[b][t][d4] -> xh[t][b][d]
        float4 v = ((const float4*)x)[i];
        half4v h = {(_Float16)v.x, (_Float16)v.y, (_Float16)v.z, (_Float16)v.w};
        unsigned d4 = (unsigned)i & 255u, t = ((unsigned)i >> 8) & 255u, b = (unsigned)i >> 16;
        ((half4v*)(xh + ((size_t)t * 64 + b) * 1024))[d4] = h;
    }
    for (size_t i = gid; i < 65536u; i += nthr) {       // zero both h rings
        half8v z = {};
        ((half8v*)hrings)[i] = z;
    }
    for (size_t i = gid; i < 139264u; i += nthr) cnts[i] = 0u;
}

// 256 blocks x 512 threads (8 waves), 1 block/CU. Blocks 0..127: cell0;
// 128..255: cell1. Wave kq owns K-slice [kq*256,+256) (cell0: k<1024 = x,
// k>=1024 = h0; cell1: h0 then h1). Weights in registers (32 x half8v).
// A held as A[2][8]. Signal: 16 leaf counters/cell/phase. Wait: wave 0
// lanes 0..31 poll leaves of BOTH dep sets + ballot, s_sleep(4) pacing.
__global__ __launch_bounds__(512, 2)
void lstm_persistent(const float* __restrict__ Wx0, const float* __restrict__ Wh0,
                     const float* __restrict__ b0,
                     const float* __restrict__ Wx1, const float* __restrict__ Wh1,
                     const float* __restrict__ b1,
                     const _Float16* __restrict__ xh, _Float16* __restrict__ h0r,
                     _Float16* __restrict__ h1r, unsigned* __restrict__ cnts,
                     float* __restrict__ out)
{
    extern __shared__ char smem[];
    _Float16* wfrag = (_Float16*)smem;           // 128 KB per staging pass
    float*    gates = (float*)smem;              // [c:64][kq:8][m:32] fp32, 64 KB
    _Float16* hlds  = (_Float16*)(smem + 65536); // [32 b][16 d] = 1 KB h gather

    const int tid  = threadIdx.x;
    const int blk  = blockIdx.x;
    const int cell = blk >> 7;
    const int wb   = blk & 127;
    const int mb   = wb >> 6, nb = wb & 63;
    const int lane = tid & 63, kq = tid >> 6;
    const int n15 = lane & 15, q = lane >> 4;

    unsigned* leaf0 = cnts;                      // [(p*16+leaf)*16]
    unsigned* leaf1 = cnts + 65536;
    unsigned* leafm = cell ? leaf1 : leaf0;

    // ---- one-time: weights -> regs via two 128KB LDS passes ----
    // pass 0: rows 0..1023   (cell0: Wx0; cell1: Wx1)  -> waves kq<4
    // pass 1: rows 1024..2047 (cell0: Wh0; cell1: Wh1) -> waves kq>=4
    half8v wreg[32];                             // [nt*8 + kt], nt 0..3
    {
        const float* passW[2] = { cell ? Wx1 : Wx0, cell ? Wh1 : Wh0 };
        for (int ps = 0; ps < 2; ++ps) {
            const float* W = passW[ps];
            for (int idx = tid; idx < 16384; idx += 512) {
                int k = idx >> 4;                // 0..1023
                int cc0 = (idx & 15) * 4;        // block-col 0..60
                const float* src = W + (size_t)k * 4096
                                   + (cc0 >> 4) * 1024 + nb * 16 + (cc0 & 15);
                float4 v = *(const float4*)src;
                int skq = k >> 8, kt = (k >> 5) & 7, qp = (k >> 3) & 3, j = k & 7;
                float vv[4] = {v.x, v.y, v.z, v.w};
                #pragma unroll
                for (int e = 0; e < 4; ++e) {
                    int cc = cc0 + e, nt = cc >> 4, nn = cc & 15;
                    wfrag[((((skq * 4 + nt) * 8 + kt) * 64) + qp * 16 + nn) * 8 + j]
                        = (_Float16)vv[e];
                }
            }
            __syncthreads();
            if ((kq >> 2) == ps) {
                int skq = kq & 3;
                #pragma unroll
                for (int nt = 0; nt < 4; ++nt)
                    #pragma unroll
                    for (int kt = 0; kt < 8; ++kt)
                        wreg[nt * 8 + kt] = *(const half8v*)
                            &wfrag[((((skq * 4 + nt) * 8 + kt) * 64) + lane) * 8];
            }
            __syncthreads();                     // wfrag reusable / gates alias
        }
    }

    const int pm = tid >> 4, pdn = tid & 15;     // pointwise coords (m, d)
    const float* bias = cell ? b1 : b0;
    const int dimg = nb * 16 + pdn;
    const float bi = bias[0 * 1024 + dimg], bfg = bias[1 * 1024 + dimg],
                bg = bias[2 * 1024 + dimg], bo  = bias[3 * 1024 + dimg];
    float creg = 0.0f;

    const bool havex = (cell == 0) && (kq < 4);  // x-wave: plain cached loads

    for (int p = 0; p <= TSTEPS; ++p) {
        if (cell == 0 && p == TSTEPS) break;
        const bool active = cell ? (p >= 1) : true;

        half8v A[2][8];
        // x burst BEFORE the poll (no coherence needed; overlaps the wait)
        if (havex) {
            const _Float16* a = xh + (size_t)p * 65536
                                + (size_t)(mb * 32 + n15) * 1024 + kq * 256 + q * 8;
            #pragma unroll
            for (int mt = 0; mt < 2; ++mt)
                #pragma unroll
                for (int kt = 0; kt < 8; ++kt)
                    A[mt][kt] = *(const half8v*)(a + mt * 16384 + kt * 32);
        }

        // ---- wait for dependencies: wave 0, leaf-parallel + ballot ----
        if (tid < 64) {
            if (p >= 1) {
                // set A: leaf0[p-1] (lanes 0..15). set B (lanes 16..31):
                //   cell0: leaf1[p-3] (ring WAR), cell1: leaf1[p-1]
                const unsigned* addr = nullptr;
                if (tid < 16) {
                    addr = leaf0 + ((p - 1) * 16 + tid) * 16;
                } else if (tid < 32) {
                    int lf = tid - 16;
                    if (cell == 0) { if (p >= 3) addr = leaf1 + ((p - 3) * 16 + lf) * 16; }
                    else           { if (p >= 2) addr = leaf1 + ((p - 1) * 16 + lf) * 16; }
                }
                bool ok = (addr == nullptr);
                while (true) {
                    if (!ok)
                        ok = __hip_atomic_load(addr, __ATOMIC_RELAXED,
                                               __HIP_MEMORY_SCOPE_AGENT) >= 8u;
                    if (__ballot(ok) == ~0ull) break;
                    __builtin_amdgcn_s_sleep(4);
                }
            }
            // ACQUIRE fence: buffer_inv -> drop possibly stale L1/L2 h lines;
            // plain cached loads below refetch from L3.
            __builtin_amdgcn_fence(__ATOMIC_ACQUIRE, "agent");
        }
        __syncthreads();

        // ---- h burst: plain cached loads from blocked ring ----
        if (active && !havex) {
            const _Float16* hb; int ks;
            if (cell == 0)   { hb = h0r + (size_t)((p - 1) & 3) * 65536; ks = kq - 4; }
            else if (kq < 4) { hb = h0r + (size_t)((p - 1) & 3) * 65536; ks = kq; }
            else             { hb = h1r + (size_t)((p - 2) & 3) * 65536; ks = kq - 4; }
            // elem (b, k): ring[mb][k>>4][b][k&15]; lane k = ks*256+kt*32+q*8+j
            const _Float16* a = hb + (size_t)mb * 32768
                                + (size_t)(ks * 16 + (q >> 1)) * 512
                                + (size_t)n15 * 16 + (q & 1) * 8;
            #pragma unroll
            for (int mt = 0; mt < 2; ++mt)
                #pragma unroll
                for (int kt = 0; kt < 8; ++kt)
                    A[mt][kt] = *(const half8v*)(a + kt * 1024 + mt * 256);
        }

        // ---- MFMA; gate partials -> swizzled LDS via ds_write_b128 ----
        if (active) {
            #pragma unroll
            for (int mt = 0; mt < 2; ++mt) {
                f32x4 acc[4] = {{0.f,0.f,0.f,0.f}, {0.f,0.f,0.f,0.f},
                                {0.f,0.f,0.f,0.f}, {0.f,0.f,0.f,0.f}};
                #pragma unroll
                for (int kt = 0; kt < 8; ++kt)
                    #pragma unroll
                    for (int nt = 0; nt < 4; ++nt)
                        acc[nt] = __builtin_amdgcn_mfma_f32_16x16x32_f16(
                                      A[mt][kt], wreg[nt * 8 + kt], acc[nt], 0, 0, 0);
                const int row0 = mt * 16 + q * 4;
                #pragma unroll
                for (int nt = 0; nt < 4; ++nt) {
                    const int c = nt * 16 + n15;
                    // gates idx = (c*8 + kq)*32 + (m ^ ((c&7)<<2)); m=row0..+3
                    *(f32x4*)(gates + (c * 8 + kq) * 32
                                    + (row0 ^ ((c & 7) << 2))) = acc[nt];
                }
            }
        }
        __syncthreads();

        // ---- pointwise: reduce 8 partials/gate, fast tanh, gather h ----
        if (active) {
            float gg[4];
            #pragma unroll
            for (int g = 0; g < 4; ++g) {
                const int c = g * 16 + pdn;
                const int key = (c & 7) << 2;
                float s = 0.f;
                #pragma unroll
                for (int k8 = 0; k8 < 8; ++k8)
                    s += gates[(c * 8 + k8) * 32 + (pm ^ key)];
                gg[g] = s;
            }
            float g0 = gg[0] + bi, g1 = gg[1] + bfg, g2 = gg[2] + bg, g3 = gg[3] + bo;
            float si = 1.f / (1.f + __expf(-g0));
            float sf = 1.f / (1.f + __expf(-g1));
            float so = 1.f / (1.f + __expf(-g3));
            float tg = 1.f - 2.f / (__expf(2.f * g2) + 1.f);
            float cn = sf * creg + si * tg;
            float tc = 1.f - 2.f / (__expf(2.f * cn) + 1.f);
            float hn = so * tc;
            creg = cn;
            hlds[tid] = (_Float16)hn;            // [m][d] = tid
            if (cell && p == TSTEPS) out[(mb * 32 + pm) * 1024 + nb * 16 + pdn] = hn;
        }

        // ---- h store (blocked, contiguous 1KB) + signal ----
        if (p < TSTEPS) {
            if (active) __syncthreads();         // hlds visible to wave 0
            if (tid < 64) {
                if (active) {
                    const u64* hp = (const u64*)(hlds + tid * 8);
                    u64 lo = hp[0], hi = hp[1];
                    _Float16* dst = (cell ? h1r + (size_t)((p - 1) & 3) * 65536
                                          : h0r + (size_t)(p & 3) * 65536)
                                    + (size_t)mb * 32768 + (size_t)nb * 512;
                    u64* dp = (u64*)dst + tid * 2;   // lane-contiguous 16B
                    __hip_atomic_store(dp,     lo, __ATOMIC_RELAXED, __HIP_MEMORY_SCOPE_AGENT);
                    __hip_atomic_store(dp + 1, hi, __ATOMIC_RELAXED, __HIP_MEMORY_SCOPE_AGENT);
                    asm volatile("s_waitcnt vmcnt(0)" ::: "memory");   // h at L3
                }
                if (tid == 0)
                    __hip_atomic_fetch_add(leafm + (p * 16 + (wb >> 3)) * 16, 1u,
                                           __ATOMIC_RELAXED, __HIP_MEMORY_SCOPE_AGENT);
            }
        }
    }
}

extern "C" void kernel_launch(void* const* d_in, const int* in_sizes, int n_in,
                              void* d_out, int out_size, void* d_ws, size_t ws_size,
                              hipStream_t stream)
{
    const float* x   = (const float*)d_in[0];
    const float* Wx0 = (const float*)d_in[1];
    const float* Wh0 = (const float*)d_in[2];
    const float* b0  = (const float*)d_in[3];
    const float* Wx1 = (const float*)d_in[4];
    const float* Wh1 = (const float*)d_in[5];
    const float* b1  = (const float*)d_in[6];
    float* out = (float*)d_out;

    _Float16* xh   = (_Float16*)d_ws;
    _Float16* h0r  = xh + (size_t)16777216;
    _Float16* h1r  = h0r + 262144;
    unsigned* cnts = (unsigned*)(h1r + 262144);

    hipLaunchKernelGGL(prologue, dim3(2048), dim3(256), 0, stream, x, xh, h0r, cnts);

    size_t smem = 131072;
    (void)hipFuncSetAttribute((const void*)lstm_persistent,
                              hipFuncAttributeMaxDynamicSharedMemorySize, (int)smem);

    void* args[] = {(void*)&Wx0, (void*)&Wh0, (void*)&b0,
                    (void*)&Wx1, (void*)&Wh1, (void*)&b1,
                    (void*)&xh, (void*)&h0r, (void*)&h1r,
                    (void*)&cnts, (void*)&out};
    (void)hipLaunchCooperativeKernel((const void*)lstm_persistent, dim3(256), dim3(512),
                                     args, (unsigned)smem, stream);
}